// Round 1
// baseline (18405.508 us; speedup 1.0000x reference)
//
#include <hip/hip_runtime.h>
#include <cstddef>

namespace {

constexpr int B  = 4;
constexpr int C  = 768;
constexpr int T  = 512;
constexpr int H  = 12;
constexpr int D  = 64;
constexpr int NL = 6;
constexpr int W  = 4;
constexpr int FF = 3072;

__device__ inline float wred_max(float v) {
#pragma unroll
  for (int o = 32; o > 0; o >>= 1) v = fmaxf(v, __shfl_xor(v, o));
  return v;
}
__device__ inline float wred_sum(float v) {
#pragma unroll
  for (int o = 32; o > 0; o >>= 1) v += __shfl_xor(v, o);
  return v;
}
__device__ inline float gelu_exact(float x) {
  return 0.5f * x * (1.0f + erff(x * 0.70710678118654752440f));
}

// out[b,o,t] = sum_{c,kk} w[o,c,kk] * in[b,c,t+kk-KSIZE/2] + bias[o]
// optional input mask multiply, GELU, output mask multiply.
template <int KSIZE, bool GELU, bool MASK_IN, bool MASK_OUT>
__global__ __launch_bounds__(256) void conv_gemm(
    const float* __restrict__ in,    // [B, Cin, T]
    const float* __restrict__ w,     // [O, Cin, KSIZE]
    const float* __restrict__ bias,  // [O]
    const float* __restrict__ mask,  // [B, T]
    float* __restrict__ out,         // [B, O, T]
    int Cin, int O)
{
  constexpr int TM = 64, TN = 64, TK = 16;
  constexpr int HP = KSIZE / 2;
  __shared__ float Aw[KSIZE][TK][TM + 4];  // +4 keeps 16B row alignment, rotates banks
  __shared__ float Bx[KSIZE][TK][TN];

  const int b  = blockIdx.z;
  const int o0 = blockIdx.y * TM;
  const int t0 = blockIdx.x * TN;
  const int tid = threadIdx.x;
  const int tx = tid & 15, ty = tid >> 4;

  const float* inb = in + (size_t)b * Cin * T;
  float acc[4][4] = {};

  for (int c0 = 0; c0 < Cin; c0 += TK) {
    // A tile: global contiguous over (ci,kk) within each o-row -> coalesced
    for (int e = tid; e < TM * TK * KSIZE; e += 256) {
      int oi = e / (TK * KSIZE);
      int r  = e % (TK * KSIZE);
      int ci = r / KSIZE;
      int kk = r % KSIZE;
      Aw[kk][ci][oi] = w[(size_t)(o0 + oi) * Cin * KSIZE + (size_t)(c0 + ci) * KSIZE + kk];
    }
    // B planes: one shifted copy of x-tile per kernel tap
    for (int e = tid; e < KSIZE * TK * TN; e += 256) {
      int kk = e / (TK * TN);
      int r  = e % (TK * TN);
      int ci = r / TN;
      int j  = r % TN;
      int t  = t0 + j + kk - HP;
      float v = 0.f;
      if (t >= 0 && t < T) {
        v = inb[(size_t)(c0 + ci) * T + t];
        if (MASK_IN) v *= mask[b * T + t];
      }
      Bx[kk][ci][j] = v;
    }
    __syncthreads();
#pragma unroll
    for (int kk = 0; kk < KSIZE; ++kk) {
#pragma unroll
      for (int kc = 0; kc < TK; ++kc) {
        const float4 a4 = *reinterpret_cast<const float4*>(&Aw[kk][kc][ty * 4]);
        const float4 b4 = *reinterpret_cast<const float4*>(&Bx[kk][kc][tx * 4]);
        const float av[4] = {a4.x, a4.y, a4.z, a4.w};
        const float bv[4] = {b4.x, b4.y, b4.z, b4.w};
#pragma unroll
        for (int i = 0; i < 4; ++i)
#pragma unroll
          for (int j = 0; j < 4; ++j)
            acc[i][j] = fmaf(av[i], bv[j], acc[i][j]);
      }
    }
    __syncthreads();
  }

  const int ob = o0 + ty * 4;
  const int tb = t0 + tx * 4;
  float bi[4];
#pragma unroll
  for (int i = 0; i < 4; ++i) bi[i] = bias[ob + i];
  float mk[4];
  if (MASK_OUT) {
#pragma unroll
    for (int j = 0; j < 4; ++j) mk[j] = mask[b * T + tb + j];
  }
#pragma unroll
  for (int i = 0; i < 4; ++i) {
    float vals[4];
#pragma unroll
    for (int j = 0; j < 4; ++j) {
      float v = acc[i][j] + bi[i];
      if (GELU) v = gelu_exact(v);
      if (MASK_OUT) v *= mk[j];
      vals[j] = v;
    }
    *reinterpret_cast<float4*>(&out[((size_t)b * O + ob + i) * T + tb]) =
        make_float4(vals[0], vals[1], vals[2], vals[3]);
  }
}

// qek[bh,t,j] = sum_d q[b,h*D+d,t]/8 * ek[d,j]
__global__ __launch_bounds__(512) void qek_kernel(
    const float* __restrict__ q, const float* __restrict__ ek,
    float* __restrict__ qek)
{
  const int bh = blockIdx.x;
  const int b = bh / H, h = bh % H;
  __shared__ float eks[D * 9];
  for (int e = threadIdx.x; e < D * 9; e += 512) eks[e] = ek[e];
  __syncthreads();
  const int t = threadIdx.x;
  const float* qb = q + ((size_t)b * C + h * D) * T;
  float acc[9] = {};
  for (int d = 0; d < D; ++d) {
    float qv = qb[(size_t)d * T + t] * 0.125f;
#pragma unroll
    for (int j = 0; j < 9; ++j) acc[j] = fmaf(qv, eks[d * 9 + j], acc[j]);
  }
  float* o = qek + ((size_t)bh * T + t) * 9;
#pragma unroll
  for (int j = 0; j < 9; ++j) o[j] = acc[j];
}

// scores[bh,t,s] = qk/8 + band(qek) masked
__global__ __launch_bounds__(256) void scores_kernel(
    const float* __restrict__ q, const float* __restrict__ k,
    const float* __restrict__ qek, const float* __restrict__ mask,
    float* __restrict__ scores)
{
  constexpr int TT = 64, TK = 16;
  __shared__ float Qs[TK][TT];
  __shared__ float Ks[TK][TT];
  const int bh = blockIdx.z;
  const int b = bh / H, h = bh % H;
  const int t0 = blockIdx.y * TT;
  const int s0 = blockIdx.x * TT;
  const int tid = threadIdx.x;
  const int tx = tid & 15, ty = tid >> 4;
  const float* qb = q + ((size_t)b * C + h * D) * T;
  const float* kb = k + ((size_t)b * C + h * D) * T;
  float acc[4][4] = {};
  for (int d0 = 0; d0 < D; d0 += TK) {
    for (int e = tid; e < TK * TT; e += 256) {
      int ci = e / TT, j = e % TT;
      Qs[ci][j] = qb[(size_t)(d0 + ci) * T + t0 + j];
      Ks[ci][j] = kb[(size_t)(d0 + ci) * T + s0 + j];
    }
    __syncthreads();
#pragma unroll
    for (int kc = 0; kc < TK; ++kc) {
      const float4 a4 = *reinterpret_cast<const float4*>(&Qs[kc][ty * 4]);
      const float4 b4 = *reinterpret_cast<const float4*>(&Ks[kc][tx * 4]);
      const float av[4] = {a4.x, a4.y, a4.z, a4.w};
      const float bv[4] = {b4.x, b4.y, b4.z, b4.w};
#pragma unroll
      for (int i = 0; i < 4; ++i)
#pragma unroll
        for (int j = 0; j < 4; ++j)
          acc[i][j] = fmaf(av[i], bv[j], acc[i][j]);
    }
    __syncthreads();
  }
  const int tb = t0 + ty * 4;
  const int sb = s0 + tx * 4;
  float mt[4], ms[4];
#pragma unroll
  for (int i = 0; i < 4; ++i) mt[i] = mask[b * T + tb + i];
#pragma unroll
  for (int j = 0; j < 4; ++j) ms[j] = mask[b * T + sb + j];
#pragma unroll
  for (int i = 0; i < 4; ++i) {
    const int t = tb + i;
    float vals[4];
#pragma unroll
    for (int j = 0; j < 4; ++j) {
      const int s = sb + j;
      float v = acc[i][j] * 0.125f;
      const int dt = s - t;
      if (dt >= -W && dt <= W) v += qek[((size_t)bh * T + t) * 9 + dt + W];
      vals[j] = (mt[i] * ms[j] == 0.f) ? -10000.0f : v;
    }
    *reinterpret_cast<float4*>(&scores[((size_t)bh * T + t) * T + sb]) =
        make_float4(vals[0], vals[1], vals[2], vals[3]);
  }
}

// in-place row softmax over last dim (T=512), one block per row
__global__ __launch_bounds__(256) void softmax_kernel(float* __restrict__ p)
{
  float* pr = p + (size_t)blockIdx.x * T;
  const int tid = threadIdx.x;
  const int lane = tid & 63, wid = tid >> 6;
  float2 v2 = *reinterpret_cast<const float2*>(pr + tid * 2);
  __shared__ float rbuf[4];
  float m = wred_max(fmaxf(v2.x, v2.y));
  if (lane == 0) rbuf[wid] = m;
  __syncthreads();
  m = fmaxf(fmaxf(rbuf[0], rbuf[1]), fmaxf(rbuf[2], rbuf[3]));
  float e0 = __expf(v2.x - m);
  float e1 = __expf(v2.y - m);
  float s = wred_sum(e0 + e1);
  __syncthreads();
  if (lane == 0) rbuf[wid] = s;
  __syncthreads();
  s = rbuf[0] + rbuf[1] + rbuf[2] + rbuf[3];
  const float inv = 1.f / s;
  *reinterpret_cast<float2*>(pr + tid * 2) = make_float2(e0 * inv, e1 * inv);
}

// out[b,h*D+d,t] = sum_s p[bh,t,s] v[b,h*D+d,s]  + band: sum_j p[t,t+j-4]*ev[d,j]
__global__ __launch_bounds__(256) void pv_kernel(
    const float* __restrict__ p, const float* __restrict__ v,
    const float* __restrict__ ev, float* __restrict__ out)
{
  constexpr int TK = 32, TM = 64, TN = 64;
  __shared__ float Vs[TK][TM + 4];
  __shared__ float Ps[TK][TN + 4];
  __shared__ float evs[D][9];
  const int bh = blockIdx.y;
  const int b = bh / H, h = bh % H;
  const int t0 = blockIdx.x * TN;
  const int tid = threadIdx.x;
  const int tx = tid & 15, ty = tid >> 4;
  const float* vb = v + ((size_t)b * C + h * D) * T;
  const float* pb = p + (size_t)bh * T * T;
  for (int e = tid; e < D * 9; e += 256) evs[e / 9][e % 9] = ev[e];
  float acc[4][4] = {};
  for (int s0 = 0; s0 < T; s0 += TK) {
    for (int e = tid; e < TK * TM; e += 256) {
      int m = e / TK, kc = e % TK;
      Vs[kc][m] = vb[(size_t)m * T + s0 + kc];
    }
    for (int e = tid; e < TK * TN; e += 256) {
      int n = e / TK, kc = e % TK;
      Ps[kc][n] = pb[(size_t)(t0 + n) * T + s0 + kc];
    }
    __syncthreads();
#pragma unroll
    for (int kc = 0; kc < TK; ++kc) {
      const float4 a4 = *reinterpret_cast<const float4*>(&Vs[kc][ty * 4]);
      const float4 b4 = *reinterpret_cast<const float4*>(&Ps[kc][tx * 4]);
      const float av[4] = {a4.x, a4.y, a4.z, a4.w};
      const float bv[4] = {b4.x, b4.y, b4.z, b4.w};
#pragma unroll
      for (int i = 0; i < 4; ++i)
#pragma unroll
        for (int j = 0; j < 4; ++j)
          acc[i][j] = fmaf(av[i], bv[j], acc[i][j]);
    }
    __syncthreads();
  }
  const int db = ty * 4;
  const int tb = t0 + tx * 4;
#pragma unroll
  for (int i = 0; i < 4; ++i) {
    const int d = db + i;
    float vals[4];
#pragma unroll
    for (int j = 0; j < 4; ++j) {
      const int t = tb + j;
      float vv = acc[i][j];
#pragma unroll
      for (int jj = 0; jj < 9; ++jj) {
        const int s = t + jj - W;
        if (s >= 0 && s < T) vv += pb[(size_t)t * T + s] * evs[d][jj];
      }
      vals[j] = vv;
    }
    *reinterpret_cast<float4*>(&out[((size_t)b * C + h * D + d) * T + tb]) =
        make_float4(vals[0], vals[1], vals[2], vals[3]);
  }
}

// dst = LayerNorm_C(x + y) * g + b   (optionally * mask). x/dst may alias.
template <bool MASK_OUT>
__global__ __launch_bounds__(256) void add_norm_kernel(
    const float* x, const float* y,
    const float* __restrict__ g, const float* __restrict__ bta,
    const float* __restrict__ mask, float* dst)
{
  const int b = blockIdx.y;
  const int t0 = blockIdx.x * 16;
  const int r = threadIdx.x >> 4, tc = threadIdx.x & 15;
  const int t = t0 + tc;
  const float* xb = x + (size_t)b * C * T;
  const float* yb = y + (size_t)b * C * T;
  float sum = 0.f, sq = 0.f;
  for (int ci = r; ci < C; ci += 16) {
    float v = xb[(size_t)ci * T + t] + yb[(size_t)ci * T + t];
    sum += v;
    sq = fmaf(v, v, sq);
  }
  __shared__ float ssum[16][17], ssq[16][17];
  __shared__ float mean_s[16], rstd_s[16];
  ssum[r][tc] = sum;
  ssq[r][tc] = sq;
  __syncthreads();
  if (r == 0) {
    float s = 0.f, q2 = 0.f;
#pragma unroll
    for (int i = 0; i < 16; ++i) { s += ssum[i][tc]; q2 += ssq[i][tc]; }
    const float m = s / C;
    mean_s[tc] = m;
    rstd_s[tc] = rsqrtf(q2 / C - m * m + 1e-5f);
  }
  __syncthreads();
  const float m = mean_s[tc], rs = rstd_s[tc];
  const float mk = MASK_OUT ? mask[b * T + t] : 1.f;
  float* db = dst + (size_t)b * C * T;
  for (int ci = r; ci < C; ci += 16) {
    float v = xb[(size_t)ci * T + t] + yb[(size_t)ci * T + t];
    float o = (v - m) * rs * g[ci] + bta[ci];
    if (MASK_OUT) o *= mk;
    db[(size_t)ci * T + t] = o;
  }
}

}  // namespace

extern "C" void kernel_launch(void* const* d_in, const int* in_sizes, int n_in,
                              void* d_out, int out_size, void* d_ws, size_t ws_size,
                              hipStream_t stream) {
  const float* x_in = (const float*)d_in[0];
  const float* mask = (const float*)d_in[1];
  const float* Wq = (const float*)d_in[2];
  const float* bq = (const float*)d_in[3];
  const float* Wk = (const float*)d_in[4];
  const float* bk = (const float*)d_in[5];
  const float* Wv = (const float*)d_in[6];
  const float* bv = (const float*)d_in[7];
  const float* Wo = (const float*)d_in[8];
  const float* bo = (const float*)d_in[9];
  const float* ek = (const float*)d_in[10];
  const float* ev = (const float*)d_in[11];
  const float* w1 = (const float*)d_in[12];
  const float* b1 = (const float*)d_in[13];
  const float* w2 = (const float*)d_in[14];
  const float* b2 = (const float*)d_in[15];
  const float* n1g = (const float*)d_in[16];
  const float* n1b = (const float*)d_in[17];
  const float* n2g = (const float*)d_in[18];
  const float* n2b = (const float*)d_in[19];

  float* ws = (float*)d_ws;
  const size_t SZ_X = (size_t)B * C * T;          // 1,572,864
  float* qb  = ws;
  float* kb  = qb + SZ_X;
  float* vb  = kb + SZ_X;
  float* sc  = vb + SZ_X;                          // B*H*T*T = 12,582,912
  float* hid = sc + (size_t)B * H * T * T;         // B*FF*T  = 6,291,456 (also attn-out)
  float* yb  = hid + (size_t)B * FF * T;
  float* xb  = yb + SZ_X;
  float* qe  = xb + SZ_X;                          // B*H*T*9
  float* outp = (float*)d_out;

  const dim3 blk(256);
  for (int i = 0; i < NL; ++i) {
    const float* xs = (i == 0) ? x_in : xb;
    const size_t wOff = (size_t)i * C * C;
    conv_gemm<1, false, false, false><<<dim3(T / 64, C / 64, B), blk, 0, stream>>>(
        xs, Wq + wOff, bq + i * C, mask, qb, C, C);
    conv_gemm<1, false, false, false><<<dim3(T / 64, C / 64, B), blk, 0, stream>>>(
        xs, Wk + wOff, bk + i * C, mask, kb, C, C);
    conv_gemm<1, false, false, false><<<dim3(T / 64, C / 64, B), blk, 0, stream>>>(
        xs, Wv + wOff, bv + i * C, mask, vb, C, C);
    qek_kernel<<<B * H, 512, 0, stream>>>(qb, ek + (size_t)i * D * (2 * W + 1), qe);
    scores_kernel<<<dim3(T / 64, T / 64, B * H), blk, 0, stream>>>(qb, kb, qe, mask, sc);
    softmax_kernel<<<B * H * T, blk, 0, stream>>>(sc);
    pv_kernel<<<dim3(T / 64, B * H), blk, 0, stream>>>(sc, vb, ev + (size_t)i * D * (2 * W + 1), hid);
    conv_gemm<1, false, false, false><<<dim3(T / 64, C / 64, B), blk, 0, stream>>>(
        hid, Wo + wOff, bo + i * C, mask, yb, C, C);
    add_norm_kernel<false><<<dim3(T / 16, B), blk, 0, stream>>>(
        xs, yb, n1g + i * C, n1b + i * C, mask, xb);
    conv_gemm<3, true, true, false><<<dim3(T / 64, FF / 64, B), blk, 0, stream>>>(
        xb, w1 + (size_t)i * FF * C * 3, b1 + i * FF, mask, hid, C, FF);
    conv_gemm<3, false, true, true><<<dim3(T / 64, C / 64, B), blk, 0, stream>>>(
        hid, w2 + (size_t)i * C * FF * 3, b2 + i * C, mask, yb, FF, C);
    add_norm_kernel<true><<<dim3(T / 16, B), blk, 0, stream>>>(
        xb, yb, n2g + i * C, n2b + i * C, mask, (i == NL - 1) ? outp : xb);
  }
}

// Round 2
// 3127.072 us; speedup vs baseline: 5.8859x; 5.8859x over previous
//
#include <hip/hip_runtime.h>
#include <cstddef>

namespace {

constexpr int B  = 4;
constexpr int C  = 768;
constexpr int T  = 512;
constexpr int H  = 12;
constexpr int D  = 64;
constexpr int NL = 6;
constexpr int W  = 4;
constexpr int FF = 3072;

typedef __attribute__((ext_vector_type(8))) short sh8;
typedef __attribute__((ext_vector_type(4))) float f32x4;

__device__ inline float wred_max(float v) {
#pragma unroll
  for (int o = 32; o > 0; o >>= 1) v = fmaxf(v, __shfl_xor(v, o));
  return v;
}
__device__ inline float wred_sum(float v) {
#pragma unroll
  for (int o = 32; o > 0; o >>= 1) v += __shfl_xor(v, o);
  return v;
}
__device__ inline float gelu_exact(float x) {
  return 0.5f * x * (1.0f + erff(x * 0.70710678118654752440f));
}
__device__ inline unsigned short f2b(float f) {
  unsigned u = __float_as_uint(f);
  unsigned r = (u + 0x7fffu + ((u >> 16) & 1u)) >> 16;
  return (unsigned short)r;
}

// ---------------------------------------------------------------------------
// Weight permute+convert: [O][Cin][3] fp32 -> [3][O][Cin] bf16 (w1 and w2).
__global__ __launch_bounds__(256) void cvt_conv_w(
    const float* __restrict__ s1, const float* __restrict__ s2,
    unsigned short* __restrict__ d1, unsigned short* __restrict__ d2)
{
  const int z = blockIdx.y;
  const float* src = z ? s2 : s1;
  unsigned short* dst = z ? d2 : d1;
  const int O  = z ? C : FF;
  const int Ci = z ? FF : C;
  const int Ci4 = Ci >> 2;
  const size_t idx = (size_t)blockIdx.x * 256 + threadIdx.x;
  const int o  = (int)(idx / Ci4);
  const int c4 = (int)(idx % Ci4) << 2;
  const float* s = src + ((size_t)o * Ci + c4) * 3;
  float4 f0 = *(const float4*)(s);
  float4 f1 = *(const float4*)(s + 4);
  float4 f2 = *(const float4*)(s + 8);
  const float f[12] = {f0.x, f0.y, f0.z, f0.w, f1.x, f1.y, f1.z, f1.w,
                       f2.x, f2.y, f2.z, f2.w};
#pragma unroll
  for (int tap = 0; tap < 3; ++tap) {
    ushort4 h;
    h.x = f2b(f[0 * 3 + tap]);
    h.y = f2b(f[1 * 3 + tap]);
    h.z = f2b(f[2 * 3 + tap]);
    h.w = f2b(f[3 * 3 + tap]);
    *(ushort4*)(dst + ((size_t)tap * O + o) * Ci + c4) = h;
  }
}

// ---------------------------------------------------------------------------
// MFMA conv/GEMM: out[b,o,t] = sum_{c,kk} w[kk][o][c] * in[b,c,t+kk-HP] (+bias)
// Tile: BM=128 (o) x BN=64 (t), BK=32, 4 waves as 2x2 (each 64x32 = 4x2 frags).
// A in LDS: [TAPS][128][32] bf16 (64B rows). B in LDS: [ROWS][40] bf16
// (t-major, transposed from [c][t] global; 80B pitch -> conflict-optimal).
// SPLIT: blockIdx.z = b*3+kk, single tap, atomicAdd epilogue (w2 split-K).
template <int TAPS, bool SPLIT, bool ABF16, bool GELU, bool MASK_IN, bool MASK_OUT>
__global__ __launch_bounds__(256) void mfma_conv(
    const float* __restrict__ inx,                 // [B][Cin][T]
    const float* __restrict__ wf0, const float* __restrict__ wf1,
    const float* __restrict__ wf2,                 // fp32 weights (per plane)
    const unsigned short* __restrict__ wbf,        // bf16 [3][O][Cin] (FFN)
    const float* __restrict__ b0, const float* __restrict__ b1,
    const float* __restrict__ b2,
    const float* __restrict__ mask,                // [B][T]
    float* __restrict__ o0p, float* __restrict__ o1p, float* __restrict__ o2p,
    int Cin, int O, int tilesPerPlane)
{
  constexpr int BM = 128, BN = 64, BK = 32;
  constexpr int ROWS_B = SPLIT ? BN : (BN + TAPS - 1);
  __shared__ unsigned short Aw[TAPS * BM * BK];
  __shared__ unsigned short Bx[ROWS_B * 40];

  const int zz = blockIdx.z;
  const int b  = SPLIT ? zz / 3 : zz;
  const int kk = SPLIT ? zz % 3 : 0;
  const int TOFF = SPLIT ? (kk - 1) : (TAPS == 3 ? -1 : 0);
  const int t0 = blockIdx.x * BN;
  const int plane = blockIdx.y / tilesPerPlane;
  const int o0 = (blockIdx.y % tilesPerPlane) * BM;

  const int tid = threadIdx.x;
  const int lane = tid & 63, wid = tid >> 6;
  const int wm = wid >> 1, wn = wid & 1;
  const int l15 = lane & 15, lhi = lane >> 4;
  const size_t xbase = (size_t)b * Cin * T;
  const int bmask = b * T;

  const float* wsel = plane == 0 ? wf0 : (plane == 1 ? wf1 : wf2);
  const unsigned short* wb_base =
      ABF16 ? (wbf + (SPLIT ? (size_t)kk * O * Cin : 0)) : nullptr;

  f32x4 acc[4][2] = {};

  for (int c0 = 0; c0 < Cin; c0 += BK) {
    __syncthreads();
    // ---- stage A (weights) ----
    if constexpr (ABF16) {
#pragma unroll
      for (int j = 0; j < TAPS * 2; ++j) {
        const int q = tid + (j << 8);
        const int tap = q >> 9;
        const int rem = q & 511;
        const int row = rem >> 2, ch = rem & 3;
        sh8 v = *(const sh8*)(wb_base + (size_t)tap * O * Cin +
                              (size_t)(o0 + row) * Cin + c0 + (ch << 3));
        *(sh8*)(&Aw[(tap << 12) + (row << 5) + (ch << 3)]) = v;
      }
    } else {
#pragma unroll
      for (int j = 0; j < 4; ++j) {
        const int q = tid + (j << 8);
        const int row = q >> 3, ch = q & 7;
        float4 f = *(const float4*)(wsel + (size_t)(o0 + row) * Cin + c0 + (ch << 2));
        ushort4 h = {f2b(f.x), f2b(f.y), f2b(f.z), f2b(f.w)};
        *(ushort4*)(&Aw[(row << 5) + (ch << 2)]) = h;
      }
    }
    // ---- stage B (activations, transposed + cvt) ----
    {
      const int c8 = (tid >> 6) << 3;
      for (int t = tid & 63; t < ROWS_B; t += 64) {
        const int tsrc = t0 + t + TOFF;
        sh8 u = (sh8)0;
        if (tsrc >= 0 && tsrc < T) {
          float vm = 1.f;
          if (MASK_IN) vm = mask[bmask + tsrc];
          const float* xp = inx + xbase + (size_t)(c0 + c8) * T + tsrc;
#pragma unroll
          for (int j = 0; j < 8; ++j) {
            float v = xp[(size_t)j * T];
            if (MASK_IN) v *= vm;
            u[j] = (short)f2b(v);
          }
        }
        *(sh8*)(&Bx[t * 40 + c8]) = u;
      }
    }
    __syncthreads();
    // ---- MFMA ----
    sh8 af[TAPS][4], bf[TAPS][2];
#pragma unroll
    for (int tap = 0; tap < TAPS; ++tap) {
#pragma unroll
      for (int m = 0; m < 4; ++m)
        af[tap][m] = *(const sh8*)(&Aw[(tap << 12) +
                                       ((wm * 64 + m * 16 + l15) << 5) + (lhi << 3)]);
#pragma unroll
      for (int n = 0; n < 2; ++n)
        bf[tap][n] = *(const sh8*)(&Bx[(wn * 32 + n * 16 + l15 +
                                        (SPLIT ? 0 : tap)) * 40 + (lhi << 3)]);
    }
#pragma unroll
    for (int tap = 0; tap < TAPS; ++tap)
#pragma unroll
      for (int m = 0; m < 4; ++m)
#pragma unroll
        for (int n = 0; n < 2; ++n)
          acc[m][n] = __builtin_amdgcn_mfma_f32_16x16x32_bf16(
              af[tap][m], bf[tap][n], acc[m][n], 0, 0, 0);
  }

  // ---- epilogue ----
  const float* bp = plane == 0 ? b0 : (plane == 1 ? b1 : b2);
  float* op = (plane == 0 ? o0p : (plane == 1 ? o1p : o2p)) + (size_t)b * O * T;
#pragma unroll
  for (int m = 0; m < 4; ++m) {
    const int o = o0 + wm * 64 + m * 16 + (lhi << 2);
#pragma unroll
    for (int n = 0; n < 2; ++n) {
      const int t = t0 + wn * 32 + n * 16 + l15;
      float mk = 1.f;
      if (MASK_OUT) mk = mask[bmask + t];
#pragma unroll
      for (int r = 0; r < 4; ++r) {
        float v = acc[m][n][r];
        if (SPLIT) {
          if (kk == 0) v += bp[o + r];
        } else {
          v += bp[o + r];
        }
        if (GELU) v = gelu_exact(v);
        if (MASK_OUT) v *= mk;
        float* ap = op + (size_t)(o + r) * T + t;
        if (SPLIT) atomicAdd(ap, v);
        else *ap = v;
      }
    }
  }
}

// ---------------------------------------------------------------------------
// qek[bh,t,j] = sum_d q[b,h*D+d,t]/8 * ek[d,j]
__global__ __launch_bounds__(512) void qek_kernel(
    const float* __restrict__ q, const float* __restrict__ ek,
    float* __restrict__ qek)
{
  const int bh = blockIdx.x;
  const int b = bh / H, h = bh % H;
  __shared__ float eks[D * 9];
  for (int e = threadIdx.x; e < D * 9; e += 512) eks[e] = ek[e];
  __syncthreads();
  const int t = threadIdx.x;
  const float* qb = q + ((size_t)b * C + h * D) * T;
  float acc[9] = {};
  for (int d = 0; d < D; ++d) {
    float qv = qb[(size_t)d * T + t] * 0.125f;
#pragma unroll
    for (int j = 0; j < 9; ++j) acc[j] = fmaf(qv, eks[d * 9 + j], acc[j]);
  }
  float* o = qek + ((size_t)bh * T + t) * 9;
#pragma unroll
  for (int j = 0; j < 9; ++j) o[j] = acc[j];
}

// scores[bh,t,s] = qk/8 + band(qek) masked
__global__ __launch_bounds__(256) void scores_kernel(
    const float* __restrict__ q, const float* __restrict__ k,
    const float* __restrict__ qek, const float* __restrict__ mask,
    float* __restrict__ scores)
{
  constexpr int TT = 64, TK = 16;
  __shared__ float Qs[TK][TT];
  __shared__ float Ks[TK][TT];
  const int bh = blockIdx.z;
  const int b = bh / H, h = bh % H;
  const int t0 = blockIdx.y * TT;
  const int s0 = blockIdx.x * TT;
  const int tid = threadIdx.x;
  const int tx = tid & 15, ty = tid >> 4;
  const float* qb = q + ((size_t)b * C + h * D) * T;
  const float* kb = k + ((size_t)b * C + h * D) * T;
  float acc[4][4] = {};
  for (int d0 = 0; d0 < D; d0 += TK) {
    for (int e = tid; e < TK * TT; e += 256) {
      int ci = e / TT, j = e % TT;
      Qs[ci][j] = qb[(size_t)(d0 + ci) * T + t0 + j];
      Ks[ci][j] = kb[(size_t)(d0 + ci) * T + s0 + j];
    }
    __syncthreads();
#pragma unroll
    for (int kc = 0; kc < TK; ++kc) {
      const float4 a4 = *reinterpret_cast<const float4*>(&Qs[kc][ty * 4]);
      const float4 b4 = *reinterpret_cast<const float4*>(&Ks[kc][tx * 4]);
      const float av[4] = {a4.x, a4.y, a4.z, a4.w};
      const float bv[4] = {b4.x, b4.y, b4.z, b4.w};
#pragma unroll
      for (int i = 0; i < 4; ++i)
#pragma unroll
        for (int j = 0; j < 4; ++j)
          acc[i][j] = fmaf(av[i], bv[j], acc[i][j]);
    }
    __syncthreads();
  }
  const int tb = t0 + ty * 4;
  const int sb = s0 + tx * 4;
  float mt[4], ms[4];
#pragma unroll
  for (int i = 0; i < 4; ++i) mt[i] = mask[b * T + tb + i];
#pragma unroll
  for (int j = 0; j < 4; ++j) ms[j] = mask[b * T + sb + j];
#pragma unroll
  for (int i = 0; i < 4; ++i) {
    const int t = tb + i;
    float vals[4];
#pragma unroll
    for (int j = 0; j < 4; ++j) {
      const int s = sb + j;
      float v = acc[i][j] * 0.125f;
      const int dt = s - t;
      if (dt >= -W && dt <= W) v += qek[((size_t)bh * T + t) * 9 + dt + W];
      vals[j] = (mt[i] * ms[j] == 0.f) ? -10000.0f : v;
    }
    *reinterpret_cast<float4*>(&scores[((size_t)bh * T + t) * T + sb]) =
        make_float4(vals[0], vals[1], vals[2], vals[3]);
  }
}

__global__ __launch_bounds__(256) void softmax_kernel(float* __restrict__ p)
{
  float* pr = p + (size_t)blockIdx.x * T;
  const int tid = threadIdx.x;
  const int lane = tid & 63, wid = tid >> 6;
  float2 v2 = *reinterpret_cast<const float2*>(pr + tid * 2);
  __shared__ float rbuf[4];
  float m = wred_max(fmaxf(v2.x, v2.y));
  if (lane == 0) rbuf[wid] = m;
  __syncthreads();
  m = fmaxf(fmaxf(rbuf[0], rbuf[1]), fmaxf(rbuf[2], rbuf[3]));
  float e0 = __expf(v2.x - m);
  float e1 = __expf(v2.y - m);
  float s = wred_sum(e0 + e1);
  __syncthreads();
  if (lane == 0) rbuf[wid] = s;
  __syncthreads();
  s = rbuf[0] + rbuf[1] + rbuf[2] + rbuf[3];
  const float inv = 1.f / s;
  *reinterpret_cast<float2*>(pr + tid * 2) = make_float2(e0 * inv, e1 * inv);
}

__global__ __launch_bounds__(256) void pv_kernel(
    const float* __restrict__ p, const float* __restrict__ v,
    const float* __restrict__ ev, float* __restrict__ out)
{
  constexpr int TK = 32, TM = 64, TN = 64;
  __shared__ float Vs[TK][TM + 4];
  __shared__ float Ps[TK][TN + 4];
  __shared__ float evs[D][9];
  const int bh = blockIdx.y;
  const int b = bh / H, h = bh % H;
  const int t0 = blockIdx.x * TN;
  const int tid = threadIdx.x;
  const int tx = tid & 15, ty = tid >> 4;
  const float* vb = v + ((size_t)b * C + h * D) * T;
  const float* pb = p + (size_t)bh * T * T;
  for (int e = tid; e < D * 9; e += 256) evs[e / 9][e % 9] = ev[e];
  float acc[4][4] = {};
  for (int s0 = 0; s0 < T; s0 += TK) {
    for (int e = tid; e < TK * TM; e += 256) {
      int m = e / TK, kc = e % TK;
      Vs[kc][m] = vb[(size_t)m * T + s0 + kc];
    }
    for (int e = tid; e < TK * TN; e += 256) {
      int n = e / TK, kc = e % TK;
      Ps[kc][n] = pb[(size_t)(t0 + n) * T + s0 + kc];
    }
    __syncthreads();
#pragma unroll
    for (int kc = 0; kc < TK; ++kc) {
      const float4 a4 = *reinterpret_cast<const float4*>(&Vs[kc][ty * 4]);
      const float4 b4 = *reinterpret_cast<const float4*>(&Ps[kc][tx * 4]);
      const float av[4] = {a4.x, a4.y, a4.z, a4.w};
      const float bv[4] = {b4.x, b4.y, b4.z, b4.w};
#pragma unroll
      for (int i = 0; i < 4; ++i)
#pragma unroll
        for (int j = 0; j < 4; ++j)
          acc[i][j] = fmaf(av[i], bv[j], acc[i][j]);
    }
    __syncthreads();
  }
  const int db = ty * 4;
  const int tb = t0 + tx * 4;
#pragma unroll
  for (int i = 0; i < 4; ++i) {
    const int d = db + i;
    float vals[4];
#pragma unroll
    for (int j = 0; j < 4; ++j) {
      const int t = tb + j;
      float vv = acc[i][j];
#pragma unroll
      for (int jj = 0; jj < 9; ++jj) {
        const int s = t + jj - W;
        if (s >= 0 && s < T) vv += pb[(size_t)t * T + s] * evs[d][jj];
      }
      vals[j] = vv;
    }
    *reinterpret_cast<float4*>(&out[((size_t)b * C + h * D + d) * T + tb]) =
        make_float4(vals[0], vals[1], vals[2], vals[3]);
  }
}

template <bool MASK_OUT>
__global__ __launch_bounds__(256) void add_norm_kernel(
    const float* x, const float* y,
    const float* __restrict__ g, const float* __restrict__ bta,
    const float* __restrict__ mask, float* dst)
{
  const int b = blockIdx.y;
  const int t0 = blockIdx.x * 16;
  const int r = threadIdx.x >> 4, tc = threadIdx.x & 15;
  const int t = t0 + tc;
  const float* xb = x + (size_t)b * C * T;
  const float* yb = y + (size_t)b * C * T;
  float sum = 0.f, sq = 0.f;
  for (int ci = r; ci < C; ci += 16) {
    float v = xb[(size_t)ci * T + t] + yb[(size_t)ci * T + t];
    sum += v;
    sq = fmaf(v, v, sq);
  }
  __shared__ float ssum[16][17], ssq[16][17];
  __shared__ float mean_s[16], rstd_s[16];
  ssum[r][tc] = sum;
  ssq[r][tc] = sq;
  __syncthreads();
  if (r == 0) {
    float s = 0.f, q2 = 0.f;
#pragma unroll
    for (int i = 0; i < 16; ++i) { s += ssum[i][tc]; q2 += ssq[i][tc]; }
    const float m = s / C;
    mean_s[tc] = m;
    rstd_s[tc] = rsqrtf(q2 / C - m * m + 1e-5f);
  }
  __syncthreads();
  const float m = mean_s[tc], rs = rstd_s[tc];
  const float mk = MASK_OUT ? mask[b * T + t] : 1.f;
  float* db = dst + (size_t)b * C * T;
  for (int ci = r; ci < C; ci += 16) {
    float v = xb[(size_t)ci * T + t] + yb[(size_t)ci * T + t];
    float o = (v - m) * rs * g[ci] + bta[ci];
    if (MASK_OUT) o *= mk;
    db[(size_t)ci * T + t] = o;
  }
}

}  // namespace

extern "C" void kernel_launch(void* const* d_in, const int* in_sizes, int n_in,
                              void* d_out, int out_size, void* d_ws, size_t ws_size,
                              hipStream_t stream) {
  const float* x_in = (const float*)d_in[0];
  const float* mask = (const float*)d_in[1];
  const float* Wq = (const float*)d_in[2];
  const float* bq = (const float*)d_in[3];
  const float* Wk = (const float*)d_in[4];
  const float* bk = (const float*)d_in[5];
  const float* Wv = (const float*)d_in[6];
  const float* bv = (const float*)d_in[7];
  const float* Wo = (const float*)d_in[8];
  const float* bo = (const float*)d_in[9];
  const float* ek = (const float*)d_in[10];
  const float* ev = (const float*)d_in[11];
  const float* w1 = (const float*)d_in[12];
  const float* b1 = (const float*)d_in[13];
  const float* w2 = (const float*)d_in[14];
  const float* b2 = (const float*)d_in[15];
  const float* n1g = (const float*)d_in[16];
  const float* n1b = (const float*)d_in[17];
  const float* n2g = (const float*)d_in[18];
  const float* n2b = (const float*)d_in[19];

  float* ws = (float*)d_ws;
  const size_t SZ_X = (size_t)B * C * T;
  float* qb  = ws;
  float* kb  = qb + SZ_X;
  float* vb  = kb + SZ_X;
  float* sc  = vb + SZ_X;                          // B*H*T*T
  float* hid = sc + (size_t)B * H * T * T;         // B*FF*T (also attn-out)
  float* yb  = hid + (size_t)B * FF * T;
  float* xb  = yb + SZ_X;
  float* qe  = xb + SZ_X;                          // B*H*T*9
  float* outp = (float*)d_out;
  // bf16 FFN weights aliased into sc (dead between pv and next scores)
  unsigned short* w1b = (unsigned short*)sc;
  unsigned short* w2b = w1b + (size_t)3 * FF * C;

  const dim3 blk(256);
  for (int i = 0; i < NL; ++i) {
    const float* xs = (i == 0) ? x_in : xb;
    const size_t wOff = (size_t)i * C * C;
    // fused QKV projection (planes selected by blockIdx.y/6)
    mfma_conv<1, false, false, false, false, false><<<dim3(8, 18, B), blk, 0, stream>>>(
        xs, Wq + wOff, Wk + wOff, Wv + wOff, nullptr,
        bq + i * C, bk + i * C, bv + i * C, mask, qb, kb, vb, C, C, 6);
    qek_kernel<<<B * H, 512, 0, stream>>>(qb, ek + (size_t)i * D * 9, qe);
    scores_kernel<<<dim3(T / 64, T / 64, B * H), blk, 0, stream>>>(qb, kb, qe, mask, sc);
    softmax_kernel<<<B * H * T, blk, 0, stream>>>(sc);
    pv_kernel<<<dim3(T / 64, B * H), blk, 0, stream>>>(sc, vb, ev + (size_t)i * D * 9, hid);
    // output projection
    mfma_conv<1, false, false, false, false, false><<<dim3(8, 6, B), blk, 0, stream>>>(
        hid, Wo + wOff, Wo + wOff, Wo + wOff, nullptr,
        bo + i * C, bo + i * C, bo + i * C, mask, yb, yb, yb, C, C, 6);
    add_norm_kernel<false><<<dim3(T / 16, B), blk, 0, stream>>>(
        xs, yb, n1g + i * C, n1b + i * C, mask, xb);
    // FFN weights -> bf16 tap-planes (into sc region, now dead)
    cvt_conv_w<<<dim3((FF * C / 4) / 256, 2), blk, 0, stream>>>(
        w1 + (size_t)i * FF * C * 3, w2 + (size_t)i * C * FF * 3, w1b, w2b);
    // FFN up: C->FF, K=3, GELU, mask-in
    mfma_conv<3, false, true, true, true, false><<<dim3(8, 24, B), blk, 0, stream>>>(
        xb, nullptr, nullptr, nullptr, w1b,
        b1 + i * FF, b1 + i * FF, b1 + i * FF, mask, hid, hid, hid, C, FF, 24);
    // FFN down: FF->C, tap-split-K with atomic accumulate
    hipMemsetAsync(yb, 0, SZ_X * sizeof(float), stream);
    mfma_conv<1, true, true, false, true, true><<<dim3(8, 6, B * 3), blk, 0, stream>>>(
        hid, nullptr, nullptr, nullptr, w2b,
        b2 + i * C, b2 + i * C, b2 + i * C, mask, yb, yb, yb, FF, C, 6);
    add_norm_kernel<true><<<dim3(T / 16, B), blk, 0, stream>>>(
        xb, yb, n2g + i * C, n2b + i * C, mask, (i == NL - 1) ? outp : xb);
  }
}

// Round 3
// 2191.428 us; speedup vs baseline: 8.3989x; 1.4270x over previous
//
#include <hip/hip_runtime.h>
#include <cstddef>

namespace {

constexpr int B  = 4;
constexpr int C  = 768;
constexpr int T  = 512;
constexpr int H  = 12;
constexpr int D  = 64;
constexpr int NL = 6;
constexpr int W  = 4;
constexpr int FF = 3072;

typedef __attribute__((ext_vector_type(8))) short sh8;
typedef __attribute__((ext_vector_type(4))) float f32x4;

__device__ inline float gelu_exact(float x) {
  return 0.5f * x * (1.0f + erff(x * 0.70710678118654752440f));
}
__device__ inline unsigned short f2b(float f) {
  unsigned u = __float_as_uint(f);
  unsigned r = (u + 0x7fffu + ((u >> 16) & 1u)) >> 16;
  return (unsigned short)r;
}
__device__ inline float b2f(unsigned short u) {
  return __uint_as_float((unsigned)u << 16);
}

// ---------------------------------------------------------------------------
// Weight permute+convert: [O][Cin][3] fp32 -> [3][O][Cin] bf16 (w1 and w2).
__global__ __launch_bounds__(256) void cvt_conv_w(
    const float* __restrict__ s1, const float* __restrict__ s2,
    unsigned short* __restrict__ d1, unsigned short* __restrict__ d2)
{
  const int z = blockIdx.y;
  const float* src = z ? s2 : s1;
  unsigned short* dst = z ? d2 : d1;
  const int O  = z ? C : FF;
  const int Ci = z ? FF : C;
  const int Ci4 = Ci >> 2;
  const size_t idx = (size_t)blockIdx.x * 256 + threadIdx.x;
  const int o  = (int)(idx / Ci4);
  const int c4 = (int)(idx % Ci4) << 2;
  const float* s = src + ((size_t)o * Ci + c4) * 3;
  float4 f0 = *(const float4*)(s);
  float4 f1 = *(const float4*)(s + 4);
  float4 f2 = *(const float4*)(s + 8);
  const float f[12] = {f0.x, f0.y, f0.z, f0.w, f1.x, f1.y, f1.z, f1.w,
                       f2.x, f2.y, f2.z, f2.w};
#pragma unroll
  for (int tap = 0; tap < 3; ++tap) {
    ushort4 h;
    h.x = f2b(f[0 * 3 + tap]);
    h.y = f2b(f[1 * 3 + tap]);
    h.z = f2b(f[2 * 3 + tap]);
    h.w = f2b(f[3 * 3 + tap]);
    *(ushort4*)(dst + ((size_t)tap * O + o) * Ci + c4) = h;
  }
}

// ---------------------------------------------------------------------------
// MFMA conv/GEMM: out[b,o,t] = sum_{c,kk} w[kk][o][c] * in[b,c,t+kk-HP] (+bias)
template <int TAPS, bool SPLIT, bool ABF16, bool GELU, bool MASK_IN, bool MASK_OUT,
          bool OBF16>
__global__ __launch_bounds__(256) void mfma_conv(
    const float* __restrict__ inx,                 // [B][Cin][T]
    const float* __restrict__ wf0, const float* __restrict__ wf1,
    const float* __restrict__ wf2,                 // fp32 weights (per plane)
    const unsigned short* __restrict__ wbf,        // bf16 [3][O][Cin] (FFN)
    const float* __restrict__ b0, const float* __restrict__ b1,
    const float* __restrict__ b2,
    const float* __restrict__ mask,                // [B][T]
    void* __restrict__ o0p, void* __restrict__ o1p, void* __restrict__ o2p,
    int Cin, int O, int tilesPerPlane)
{
  constexpr int BM = 128, BN = 64, BK = 32;
  constexpr int ROWS_B = SPLIT ? BN : (BN + TAPS - 1);
  __shared__ unsigned short Aw[TAPS * BM * BK];
  __shared__ unsigned short Bx[ROWS_B * 40];

  const int zz = blockIdx.z;
  const int b  = SPLIT ? zz / 3 : zz;
  const int kk = SPLIT ? zz % 3 : 0;
  const int TOFF = SPLIT ? (kk - 1) : (TAPS == 3 ? -1 : 0);
  const int t0 = blockIdx.x * BN;
  const int plane = blockIdx.y / tilesPerPlane;
  const int o0 = (blockIdx.y % tilesPerPlane) * BM;

  const int tid = threadIdx.x;
  const int lane = tid & 63, wid = tid >> 6;
  const int wm = wid >> 1, wn = wid & 1;
  const int l15 = lane & 15, lhi = lane >> 4;
  const size_t xbase = (size_t)b * Cin * T;
  const int bmask = b * T;

  const float* wsel = plane == 0 ? wf0 : (plane == 1 ? wf1 : wf2);
  const unsigned short* wb_base =
      ABF16 ? (wbf + (SPLIT ? (size_t)kk * O * Cin : 0)) : nullptr;

  f32x4 acc[4][2] = {};

  for (int c0 = 0; c0 < Cin; c0 += BK) {
    __syncthreads();
    // ---- stage A (weights) ----
    if constexpr (ABF16) {
#pragma unroll
      for (int j = 0; j < TAPS * 2; ++j) {
        const int q = tid + (j << 8);
        const int tap = q >> 9;
        const int rem = q & 511;
        const int row = rem >> 2, ch = rem & 3;
        sh8 v = *(const sh8*)(wb_base + (size_t)tap * O * Cin +
                              (size_t)(o0 + row) * Cin + c0 + (ch << 3));
        *(sh8*)(&Aw[(tap << 12) + (row << 5) + (ch << 3)]) = v;
      }
    } else {
#pragma unroll
      for (int j = 0; j < 4; ++j) {
        const int q = tid + (j << 8);
        const int row = q >> 3, ch = q & 7;
        float4 f = *(const float4*)(wsel + (size_t)(o0 + row) * Cin + c0 + (ch << 2));
        ushort4 h = {f2b(f.x), f2b(f.y), f2b(f.z), f2b(f.w)};
        *(ushort4*)(&Aw[(row << 5) + (ch << 2)]) = h;
      }
    }
    // ---- stage B (activations, transposed + cvt) ----
    {
      const int c8 = (tid >> 6) << 3;
      for (int t = tid & 63; t < ROWS_B; t += 64) {
        const int tsrc = t0 + t + TOFF;
        sh8 u = (sh8)0;
        if (tsrc >= 0 && tsrc < T) {
          float vm = 1.f;
          if (MASK_IN) vm = mask[bmask + tsrc];
          const float* xp = inx + xbase + (size_t)(c0 + c8) * T + tsrc;
#pragma unroll
          for (int j = 0; j < 8; ++j) {
            float v = xp[(size_t)j * T];
            if (MASK_IN) v *= vm;
            u[j] = (short)f2b(v);
          }
        }
        *(sh8*)(&Bx[t * 40 + c8]) = u;
      }
    }
    __syncthreads();
    // ---- MFMA ----
    sh8 af[TAPS][4], bf[TAPS][2];
#pragma unroll
    for (int tap = 0; tap < TAPS; ++tap) {
#pragma unroll
      for (int m = 0; m < 4; ++m)
        af[tap][m] = *(const sh8*)(&Aw[(tap << 12) +
                                       ((wm * 64 + m * 16 + l15) << 5) + (lhi << 3)]);
#pragma unroll
      for (int n = 0; n < 2; ++n)
        bf[tap][n] = *(const sh8*)(&Bx[(wn * 32 + n * 16 + l15 +
                                        (SPLIT ? 0 : tap)) * 40 + (lhi << 3)]);
    }
#pragma unroll
    for (int tap = 0; tap < TAPS; ++tap)
#pragma unroll
      for (int m = 0; m < 4; ++m)
#pragma unroll
        for (int n = 0; n < 2; ++n)
          acc[m][n] = __builtin_amdgcn_mfma_f32_16x16x32_bf16(
              af[tap][m], bf[tap][n], acc[m][n], 0, 0, 0);
  }

  // ---- epilogue ----
  const float* bp = plane == 0 ? b0 : (plane == 1 ? b1 : b2);
  void* obase = plane == 0 ? o0p : (plane == 1 ? o1p : o2p);
  float* opf = (float*)obase + (size_t)b * O * T;
  unsigned short* oph = (unsigned short*)obase + (size_t)b * O * T;
#pragma unroll
  for (int m = 0; m < 4; ++m) {
    const int o = o0 + wm * 64 + m * 16 + (lhi << 2);
#pragma unroll
    for (int n = 0; n < 2; ++n) {
      const int t = t0 + wn * 32 + n * 16 + l15;
      float mk = 1.f;
      if (MASK_OUT) mk = mask[bmask + t];
#pragma unroll
      for (int r = 0; r < 4; ++r) {
        float v = acc[m][n][r];
        if (SPLIT) {
          if (kk == 0) v += bp[o + r];
        } else {
          v += bp[o + r];
        }
        if (GELU) v = gelu_exact(v);
        if (MASK_OUT) v *= mk;
        if constexpr (OBF16) {
          oph[(size_t)(o + r) * T + t] = f2b(v);
        } else if constexpr (SPLIT) {
          atomicAdd(&opf[(size_t)(o + r) * T + t], v);
        } else {
          opf[(size_t)(o + r) * T + t] = v;
        }
      }
    }
  }
}

// ---------------------------------------------------------------------------
// Fused attention: per block (t-tile of 64, one (b,h)). 4 waves x 16 t-rows.
// Swapped QK^T (rows=s, cols=t) -> per-lane online softmax -> P in per-wave
// LDS rows -> PV with native-layout V. Rel-position k-band and v-band fused.
__global__ __launch_bounds__(256) void fused_attn(
    const unsigned short* __restrict__ qg,  // [B][C][T] bf16
    const unsigned short* __restrict__ kg,
    const unsigned short* __restrict__ vg,
    const float* __restrict__ mask,         // [B][T]
    const float* __restrict__ ek,           // [D][9]
    const float* __restrict__ ev,           // [D][9]
    float* __restrict__ outp)               // [B][C][T]
{
  constexpr int PITCH = 72;  // bf16 elems; 144B rows -> 8 distinct bank phases
  __shared__ unsigned short Qs[64 * PITCH];  // Q^T [t][d], pre-scaled 1/8
  __shared__ unsigned short Ks[64 * PITCH];  // K^T [s][d]
  __shared__ unsigned short Vs[64 * PITCH];  // V   [d][s] (native)
  __shared__ unsigned short Ps[64 * PITCH];  // P   [t][s] (per-wave rows)
  __shared__ float eks[D * 9], evs[D * 9];
  __shared__ float qekl[64 * 12];            // rel-k logits [t][j]
  __shared__ float mks[64];

  const int t0 = blockIdx.x * 64;
  const int bh = blockIdx.y;
  const int b = bh / H, h = bh % H;
  const int tid = threadIdx.x;
  const int lane = tid & 63, w = tid >> 6;
  const int l15 = lane & 15, lhi = lane >> 4;

  const size_t hoff = ((size_t)b * C + h * D) * T;
  const unsigned short* qh = qg + hoff;
  const unsigned short* kh = kg + hoff;
  const unsigned short* vh = vg + hoff;

  for (int e = tid; e < D * 9; e += 256) { eks[e] = ek[e]; evs[e] = ev[e]; }
  // stage Q^T (scaled by 1/8; used by both QK and rel-logits)
  {
    const int tl = tid & 63, d0 = (tid >> 6) << 4;
    sh8 u0, u1;
#pragma unroll
    for (int j = 0; j < 8; ++j)
      u0[j] = (short)f2b(0.125f * b2f(qh[(size_t)(d0 + j) * T + t0 + tl]));
#pragma unroll
    for (int j = 0; j < 8; ++j)
      u1[j] = (short)f2b(0.125f * b2f(qh[(size_t)(d0 + 8 + j) * T + t0 + tl]));
    *(sh8*)&Qs[tl * PITCH + d0] = u0;
    *(sh8*)&Qs[tl * PITCH + d0 + 8] = u1;
  }
  __syncthreads();
  // rel-k logits: qekl[t][j] = sum_d Qs[t][d] * ek[d][j]
  {
    const int tl = tid & 63, g = tid >> 6;
    for (int j = g; j < 9; j += 4) {
      float a = 0.f;
      for (int d = 0; d < D; ++d)
        a = fmaf(b2f(Qs[tl * PITCH + d]), eks[d * 9 + j], a);
      qekl[tl * 12 + j] = a;
    }
  }
  const int t_loc = w * 16 + l15;
  const int t = t0 + t_loc;
  const float mask_t = mask[b * T + t];
  const sh8 bq0 = *(const sh8*)&Qs[t_loc * PITCH + lhi * 8];
  const sh8 bq1 = *(const sh8*)&Qs[t_loc * PITCH + 32 + lhi * 8];

  float m_run = -1e30f, l_run = 0.f;
  f32x4 oacc[4] = {};

  for (int s0 = 0; s0 < T; s0 += 64) {
    __syncthreads();
    // stage K^T [s][d] (transpose from [d][s])
    {
      const int sl = tid & 63;
#pragma unroll
      for (int cc = 0; cc < 2; ++cc) {
        const int d0 = (((tid >> 6) << 1) + cc) << 3;
        sh8 u;
#pragma unroll
        for (int j = 0; j < 8; ++j)
          u[j] = (short)kh[(size_t)(d0 + j) * T + s0 + sl];
        *(sh8*)&Ks[sl * PITCH + d0] = u;
      }
    }
    // stage V [d][s] (native, vectorized)
    {
#pragma unroll
      for (int cc = 0; cc < 2; ++cc) {
        const int idx = tid + (cc << 8);
        const int dr = idx >> 3, ch = (idx & 7) << 3;
        sh8 u = *(const sh8*)&vh[(size_t)dr * T + s0 + ch];
        *(sh8*)&Vs[dr * PITCH + ch] = u;
      }
    }
    if (tid < 64) mks[tid] = mask[b * T + s0 + tid];
    __syncthreads();

    // QK^T (swapped): out rows = s, cols = t  -> lane holds 16 s for ONE t
    float p[16];
#pragma unroll
    for (int n = 0; n < 4; ++n) {
      const sh8 a0 = *(const sh8*)&Ks[(n * 16 + l15) * PITCH + lhi * 8];
      const sh8 a1 = *(const sh8*)&Ks[(n * 16 + l15) * PITCH + 32 + lhi * 8];
      f32x4 acc = {};
      acc = __builtin_amdgcn_mfma_f32_16x16x32_bf16(a0, bq0, acc, 0, 0, 0);
      acc = __builtin_amdgcn_mfma_f32_16x16x32_bf16(a1, bq1, acc, 0, 0, 0);
#pragma unroll
      for (int r = 0; r < 4; ++r) {
        const int s = s0 + n * 16 + lhi * 4 + r;
        float v = acc[r];
        const int j = s - t + 4;
        if ((unsigned)j < 9u) v += qekl[t_loc * 12 + j];
        if (mask_t * mks[s - s0] == 0.f) v = -10000.0f;
        p[n * 4 + r] = v;
      }
    }
    // online softmax: per-lane max/sum + 2 shuffles across the lhi groups
    float mloc = p[0];
#pragma unroll
    for (int i = 1; i < 16; ++i) mloc = fmaxf(mloc, p[i]);
    mloc = fmaxf(mloc, __shfl_xor(mloc, 16));
    mloc = fmaxf(mloc, __shfl_xor(mloc, 32));
    const float m_new = fmaxf(m_run, mloc);
    const float f = __expf(m_run - m_new);
    float sloc = 0.f;
#pragma unroll
    for (int i = 0; i < 16; ++i) { p[i] = __expf(p[i] - m_new); sloc += p[i]; }
    sloc += __shfl_xor(sloc, 16);
    sloc += __shfl_xor(sloc, 32);
    l_run = l_run * f + sloc;
    m_run = m_new;
#pragma unroll
    for (int m = 0; m < 4; ++m)
#pragma unroll
      for (int r = 0; r < 4; ++r) oacc[m][r] *= f;
    // write P (bf16) into this wave's private rows of Ps
#pragma unroll
    for (int n = 0; n < 4; ++n) {
      uint2 pk;
      pk.x = (unsigned)f2b(p[n * 4 + 0]) | ((unsigned)f2b(p[n * 4 + 1]) << 16);
      pk.y = (unsigned)f2b(p[n * 4 + 2]) | ((unsigned)f2b(p[n * 4 + 3]) << 16);
      *(uint2*)&Ps[t_loc * PITCH + n * 16 + lhi * 4] = pk;
    }
    asm volatile("s_waitcnt lgkmcnt(0)" ::: "memory");  // cross-lane P vis.
    // PV: out[d][t] += V[d][s] * P[t][s]
    const sh8 bp0 = *(const sh8*)&Ps[t_loc * PITCH + lhi * 8];
    const sh8 bp1 = *(const sh8*)&Ps[t_loc * PITCH + 32 + lhi * 8];
#pragma unroll
    for (int m = 0; m < 4; ++m) {
      const sh8 a0 = *(const sh8*)&Vs[(m * 16 + l15) * PITCH + lhi * 8];
      const sh8 a1 = *(const sh8*)&Vs[(m * 16 + l15) * PITCH + 32 + lhi * 8];
      oacc[m] = __builtin_amdgcn_mfma_f32_16x16x32_bf16(a0, bp0, oacc[m], 0, 0, 0);
      oacc[m] = __builtin_amdgcn_mfma_f32_16x16x32_bf16(a1, bp1, oacc[m], 0, 0, 0);
    }
    // v-band: out[d][t] += sum_j P[t][t+j-4] * ev[d][j]
    if (t + 4 >= s0 && t < s0 + 68) {
#pragma unroll
      for (int j = 0; j < 9; ++j) {
        const int s = t + j - 4;
        if (s >= s0 && s < s0 + 64) {
          const float pv = b2f(Ps[t_loc * PITCH + (s - s0)]);
#pragma unroll
          for (int m = 0; m < 4; ++m)
#pragma unroll
            for (int r = 0; r < 4; ++r)
              oacc[m][r] = fmaf(pv, evs[(m * 16 + lhi * 4 + r) * 9 + j], oacc[m][r]);
        }
      }
    }
  }
  const float invl = 1.f / l_run;
  float* ob = outp + ((size_t)b * C + h * D) * T + t;
#pragma unroll
  for (int m = 0; m < 4; ++m)
#pragma unroll
    for (int r = 0; r < 4; ++r)
      ob[(size_t)(m * 16 + lhi * 4 + r) * T] = oacc[m][r] * invl;
}

// ---------------------------------------------------------------------------
template <bool MASK_OUT>
__global__ __launch_bounds__(256) void add_norm_kernel(
    const float* x, const float* y,
    const float* __restrict__ g, const float* __restrict__ bta,
    const float* __restrict__ mask, float* dst)
{
  const int b = blockIdx.y;
  const int t0 = blockIdx.x * 16;
  const int r = threadIdx.x >> 4, tc = threadIdx.x & 15;
  const int t = t0 + tc;
  const float* xb = x + (size_t)b * C * T;
  const float* yb = y + (size_t)b * C * T;
  float sum = 0.f, sq = 0.f;
  for (int ci = r; ci < C; ci += 16) {
    float v = xb[(size_t)ci * T + t] + yb[(size_t)ci * T + t];
    sum += v;
    sq = fmaf(v, v, sq);
  }
  __shared__ float ssum[16][17], ssq[16][17];
  __shared__ float mean_s[16], rstd_s[16];
  ssum[r][tc] = sum;
  ssq[r][tc] = sq;
  __syncthreads();
  if (r == 0) {
    float s = 0.f, q2 = 0.f;
#pragma unroll
    for (int i = 0; i < 16; ++i) { s += ssum[i][tc]; q2 += ssq[i][tc]; }
    const float m = s / C;
    mean_s[tc] = m;
    rstd_s[tc] = rsqrtf(q2 / C - m * m + 1e-5f);
  }
  __syncthreads();
  const float m = mean_s[tc], rs = rstd_s[tc];
  const float mk = MASK_OUT ? mask[b * T + t] : 1.f;
  float* db = dst + (size_t)b * C * T;
  for (int ci = r; ci < C; ci += 16) {
    float v = xb[(size_t)ci * T + t] + yb[(size_t)ci * T + t];
    float o = (v - m) * rs * g[ci] + bta[ci];
    if (MASK_OUT) o *= mk;
    db[(size_t)ci * T + t] = o;
  }
}

}  // namespace

extern "C" void kernel_launch(void* const* d_in, const int* in_sizes, int n_in,
                              void* d_out, int out_size, void* d_ws, size_t ws_size,
                              hipStream_t stream) {
  const float* x_in = (const float*)d_in[0];
  const float* mask = (const float*)d_in[1];
  const float* Wq = (const float*)d_in[2];
  const float* bq = (const float*)d_in[3];
  const float* Wk = (const float*)d_in[4];
  const float* bk = (const float*)d_in[5];
  const float* Wv = (const float*)d_in[6];
  const float* bv = (const float*)d_in[7];
  const float* Wo = (const float*)d_in[8];
  const float* bo = (const float*)d_in[9];
  const float* ek = (const float*)d_in[10];
  const float* ev = (const float*)d_in[11];
  const float* w1 = (const float*)d_in[12];
  const float* b1 = (const float*)d_in[13];
  const float* w2 = (const float*)d_in[14];
  const float* b2 = (const float*)d_in[15];
  const float* n1g = (const float*)d_in[16];
  const float* n1b = (const float*)d_in[17];
  const float* n2g = (const float*)d_in[18];
  const float* n2b = (const float*)d_in[19];

  float* ws = (float*)d_ws;
  const size_t SZ_X = (size_t)B * C * T;
  float* hid = ws;                                  // B*FF*T (also attn out)
  float* yb  = hid + (size_t)B * FF * T;
  float* xb  = yb + SZ_X;
  unsigned short* qbh = (unsigned short*)(xb + SZ_X);   // bf16 [B][C][T]
  unsigned short* kbh = qbh + SZ_X;
  unsigned short* vbh = kbh + SZ_X;
  unsigned short* w1b = vbh + SZ_X;                 // bf16 [3][FF][C]
  unsigned short* w2b = w1b + (size_t)3 * FF * C;   // bf16 [3][C][FF]
  float* outp = (float*)d_out;

  const dim3 blk(256);
  for (int i = 0; i < NL; ++i) {
    const float* xs = (i == 0) ? x_in : xb;
    const size_t wOff = (size_t)i * C * C;
    // fused QKV projection -> bf16 q,k,v
    mfma_conv<1, false, false, false, false, false, true>
        <<<dim3(8, 18, B), blk, 0, stream>>>(
        xs, Wq + wOff, Wk + wOff, Wv + wOff, nullptr,
        bq + i * C, bk + i * C, bv + i * C, mask, qbh, kbh, vbh, C, C, 6);
    // fused attention (QK^T + rel-k band + mask + softmax + PV + rel-v band)
    fused_attn<<<dim3(T / 64, B * H), blk, 0, stream>>>(
        qbh, kbh, vbh, mask, ek + (size_t)i * D * 9, ev + (size_t)i * D * 9, hid);
    // output projection
    mfma_conv<1, false, false, false, false, false, false>
        <<<dim3(8, 6, B), blk, 0, stream>>>(
        hid, Wo + wOff, Wo + wOff, Wo + wOff, nullptr,
        bo + i * C, bo + i * C, bo + i * C, mask, yb, yb, yb, C, C, 6);
    add_norm_kernel<false><<<dim3(T / 16, B), blk, 0, stream>>>(
        xs, yb, n1g + i * C, n1b + i * C, mask, xb);
    // FFN weights -> bf16 tap-planes
    cvt_conv_w<<<dim3((FF * C / 4) / 256, 2), blk, 0, stream>>>(
        w1 + (size_t)i * FF * C * 3, w2 + (size_t)i * C * FF * 3, w1b, w2b);
    // FFN up: C->FF, K=3, GELU, mask-in
    mfma_conv<3, false, true, true, true, false, false>
        <<<dim3(8, 24, B), blk, 0, stream>>>(
        xb, nullptr, nullptr, nullptr, w1b,
        b1 + i * FF, b1 + i * FF, b1 + i * FF, mask, hid, hid, hid, C, FF, 24);
    // FFN down: FF->C, tap-split-K with atomic accumulate
    hipMemsetAsync(yb, 0, SZ_X * sizeof(float), stream);
    mfma_conv<1, true, true, false, true, true, false>
        <<<dim3(8, 6, B * 3), blk, 0, stream>>>(
        hid, nullptr, nullptr, nullptr, w2b,
        b2 + i * C, b2 + i * C, b2 + i * C, mask, yb, yb, yb, FF, C, 6);
    add_norm_kernel<true><<<dim3(T / 16, B), blk, 0, stream>>>(
        xb, yb, n2g + i * C, n2b + i * C, mask, (i == NL - 1) ? outp : xb);
  }
}